// Round 10
// baseline (95.702 us; speedup 1.0000x reference)
//
#include <hip/hip_runtime.h>

#define DPROJ 1024

typedef short  bf16x8 __attribute__((ext_vector_type(8)));
typedef float  f32x4  __attribute__((ext_vector_type(4)));

__device__ __forceinline__ unsigned short f2bf(float f) {
  unsigned u = __builtin_bit_cast(unsigned, f);
  u += 0x7FFFu + ((u >> 16) & 1u);          // round-to-nearest-even
  return (unsigned short)(u >> 16);
}

__device__ __forceinline__ bf16x8 pack8(float4 lo, float4 hi) {
  bf16x8 r;
  r[0] = (short)f2bf(lo.x); r[1] = (short)f2bf(lo.y);
  r[2] = (short)f2bf(lo.z); r[3] = (short)f2bf(lo.w);
  r[4] = (short)f2bf(hi.x); r[5] = (short)f2bf(hi.y);
  r[6] = (short)f2bf(hi.z); r[7] = (short)f2bf(hi.w);
  return r;
}

// ---------------------------------------------------------------------------
// Kernel 0: zero the 4 bucket counters.
// ---------------------------------------------------------------------------
__global__ void zero_counts(int* __restrict__ counts) {
  if (threadIdx.x < 4) counts[threadIdx.x] = 0;
}

// ---------------------------------------------------------------------------
// Kernel 1: classify tokens into 4 bucket lists. Entry packs (in-bucket row
// << 14) | token_id (n = 16384 = 2^14). Wave-aggregated atomics. List order
// nondeterministic but each token's output value is position-independent.
// ---------------------------------------------------------------------------
__global__ __launch_bounds__(256) void classify_kernel(const int* __restrict__ inp, int n,
                                                       int* __restrict__ counts,
                                                       unsigned* __restrict__ lists) {
  int t = blockIdx.x * 256 + threadIdx.x;
  int lane = threadIdx.x & 63;
  int v = (t < n) ? inp[t] : -1;
  int b = (v < 0) ? -1 : (v >= 200000) ? 3 : (v >= 40000) ? 2 : (v >= 20000) ? 1 : 0;
  int lo = (b == 3) ? 200000 : (b == 2) ? 40000 : (b == 1) ? 20000 : 0;
#pragma unroll
  for (int i = 0; i < 4; ++i) {
    unsigned long long m = __ballot(b == i);
    if (b == i) {
      int rank = __popcll(m & ((1ull << lane) - 1ull));
      int src  = __ffsll((unsigned long long)m) - 1;
      int base = 0;
      if (lane == src) base = atomicAdd(&counts[i], __popcll(m));
      base = __shfl(base, src);
      lists[i * n + base + rank] = ((unsigned)(v - lo) << 14) | (unsigned)t;
    }
  }
}

// ---------------------------------------------------------------------------
// Kernel 2: convert the 4 proj matrices fp32 -> bf16 into ws, concatenated.
// Elem offsets: p0 @0 (1048576), p1 @1048576 (262144), p2 @1310720 (65536),
// p3 @1376256 (16384); total 1392640. 8 elems/thread, fully coalesced.
// Done ONCE per launch -> the GEMM does zero B-conversion VALU, and the
// bf16 tables (2.8 MB total) fit in every XCD's 4 MB L2.
// ---------------------------------------------------------------------------
__global__ __launch_bounds__(256) void convert_proj(const float* __restrict__ p0,
                                                    const float* __restrict__ p1,
                                                    const float* __restrict__ p2,
                                                    const float* __restrict__ p3,
                                                    unsigned short* __restrict__ pb) {
  size_t base = ((size_t)blockIdx.x * 256 + threadIdx.x) * 8;
  if (base >= 1392640u) return;
  const float* src;
  if      (base < 1048576u) src = p0 + base;
  else if (base < 1310720u) src = p1 + (base - 1048576u);
  else if (base < 1376256u) src = p2 + (base - 1310720u);
  else                      src = p3 + (base - 1376256u);
  float4 lo = reinterpret_cast<const float4*>(src)[0];
  float4 hi = reinterpret_cast<const float4*>(src)[1];
  *reinterpret_cast<bf16x8*>(pb + base) = pack8(lo, hi);
}

// ---------------------------------------------------------------------------
// Kernel 3: GEMM, 16 tokens x 1024 cols per block. Each block produces its
// 16 output rows WHOLE (4 KB contiguous each) -> one L2 assembles full dirty
// rows (fill-kernel write pattern). 4 waves; wave w owns cols [w*256,+256) as
// 16 MFMA col-frags. A direct from emb f32 (16 shared rows, L1 broadcast);
// B direct 16B bf16x8 loads from the pre-converted table (each instruction:
// 16 cols x 64 B contiguous = 100% line utilization). No LDS, no barriers.
// C/D frag: col = lane&15, row = (lane>>4)*4 + reg (HW-verified r1-r9).
// ---------------------------------------------------------------------------
template <int D>
__device__ __forceinline__ void tile16(const float* __restrict__ emb,
                                       const unsigned short* __restrict__ pb,
                                       const unsigned* __restrict__ list,
                                       int cnt, int r0, float* __restrict__ out) {
  const int tid  = threadIdx.x;
  const int lane = tid & 63;
  const int w    = tid >> 6;
  const int lr   = lane & 15, t16 = lane >> 4;

  int p = r0 + lr;
  unsigned entry = (p < cnt) ? list[p] : 0u;   // pads -> row 0 (stores suppressed)
  const float* eb = emb + (size_t)(entry >> 14) * D;
  const int colbase = w * 256;

  f32x4 acc[16];
#pragma unroll
  for (int fj = 0; fj < 16; ++fj) acc[fj] = (f32x4){0.f, 0.f, 0.f, 0.f};

  constexpr int NCH = (D + 63) / 64;           // 16, 4, 1, 1
  constexpr int S   = (D >= 64) ? 2 : 1;       // K=32 steps per chunk
  const bool kvalid = (D >= 64) || (t16 < 2);  // D=16: lanes t16>=2 carry zeros
  const int  tk     = kvalid ? t16 * 8 : 0;

#pragma unroll 1
  for (int ch = 0; ch < NCH; ++ch) {
#pragma unroll
    for (int s = 0; s < S; ++s) {
      const int k0 = ch * 64 + s * 32;
      float4 alo = make_float4(0.f, 0.f, 0.f, 0.f), ahi = alo;
      if (kvalid) {
        alo = *reinterpret_cast<const float4*>(eb + k0 + t16 * 8);
        ahi = *reinterpret_cast<const float4*>(eb + k0 + t16 * 8 + 4);
      }
      bf16x8 a = pack8(alo, ahi);
      bf16x8 b[16];
#pragma unroll
      for (int fj = 0; fj < 16; ++fj) {
        int col = colbase + fj * 16 + lr;
        b[fj] = *reinterpret_cast<const bf16x8*>(pb + (size_t)col * D + k0 + tk);
      }
#pragma unroll
      for (int fj = 0; fj < 16; ++fj)
        acc[fj] = __builtin_amdgcn_mfma_f32_16x16x32_bf16(a, b[fj], acc[fj], 0, 0, 0);
    }
  }

  // epilogue: row r = t16*4+reg; token id fetched from lane r via shfl.
  // Per (reg,fj) instruction: 16 lanes write 64 B contiguous in row r's 4 KB
  // span; the whole block covers each row completely -> L2 write-merge.
#pragma unroll
  for (int reg = 0; reg < 4; ++reg) {
    int r = t16 * 4 + reg;
    unsigned er = __shfl(entry, r);
    if (r0 + r < cnt) {
      float* orow = out + (size_t)(er & 16383u) * DPROJ + colbase + lr;
#pragma unroll
      for (int fj = 0; fj < 16; ++fj) orow[fj * 16] = acc[fj][reg];
    }
  }
}

__global__ __launch_bounds__(256) void gemm16(
    const float* __restrict__ e0, const float* __restrict__ e1,
    const float* __restrict__ e2, const float* __restrict__ e3,
    const unsigned short* __restrict__ pb,
    const int* __restrict__ counts, const unsigned* __restrict__ lists,
    float* __restrict__ out, int n) {
  int4 c = *reinterpret_cast<const int4*>(counts);
  int t0 = (c.x + 15) >> 4, t1 = (c.y + 15) >> 4,
      t2 = (c.z + 15) >> 4, t3 = (c.w + 15) >> 4;
  int t = blockIdx.x;
  if (t < t0) { tile16<1024>(e0, pb,           lists,               c.x, t * 16, out); return; }
  t -= t0;
  if (t < t1) { tile16< 256>(e1, pb + 1048576, lists + (size_t)n,   c.y, t * 16, out); return; }
  t -= t1;
  if (t < t2) { tile16<  64>(e2, pb + 1310720, lists + (size_t)2*n, c.z, t * 16, out); return; }
  t -= t2;
  if (t < t3) { tile16<  16>(e3, pb + 1376256, lists + (size_t)3*n, c.w, t * 16, out); return; }
}

// ---------------------------------------------------------------------------
// Input order (setup_inputs dict order, verified rounds 1-9):
// inp, emb0, proj0, emb1, proj1, emb2, proj2, emb3, proj3.
// ws layout: [4 counts][4n packed lists][@512KB: bf16 proj tables, 2.72MB].
// ---------------------------------------------------------------------------
extern "C" void kernel_launch(void* const* d_in, const int* in_sizes, int n_in,
                              void* d_out, int out_size, void* d_ws, size_t ws_size,
                              hipStream_t stream) {
  const int*   inp   = (const int*)d_in[0];
  const float* emb0  = (const float*)d_in[1];
  const float* proj0 = (const float*)d_in[2];
  const float* emb1  = (const float*)d_in[3];
  const float* proj1 = (const float*)d_in[4];
  const float* emb2  = (const float*)d_in[5];
  const float* proj2 = (const float*)d_in[6];
  const float* emb3  = (const float*)d_in[7];
  const float* proj3 = (const float*)d_in[8];
  float* out = (float*)d_out;
  const int n = in_sizes[0];  // 16384 tokens

  int*            counts = (int*)d_ws;
  unsigned*       lists  = (unsigned*)d_ws + 4;
  unsigned short* pb     = (unsigned short*)((char*)d_ws + (1u << 19));

  zero_counts<<<dim3(1), dim3(64), 0, stream>>>(counts);
  classify_kernel<<<dim3((n + 255) / 256), dim3(256), 0, stream>>>(inp, n, counts, lists);
  convert_proj<<<dim3(680), dim3(256), 0, stream>>>(proj0, proj1, proj2, proj3, pb);

  // tiles: sum_i ceil(cnt_i/16) <= n/16 + 3 = 1027; dead blocks exit on the
  // counts read. No XCD grouping: round-robin spreads blocks so every XCD's
  // L2 keeps its own copy of the (2.8 MB) bf16 proj tables.
  gemm16<<<dim3(1028), dim3(256), 0, stream>>>(emb0, emb1, emb2, emb3, pb,
                                               counts, lists, out, n);
}

// Round 12
// 42.786 us; speedup vs baseline: 2.2367x; 2.2367x over previous
//
#include <hip/hip_runtime.h>

#define DPROJ 1024

typedef short  bf16x8 __attribute__((ext_vector_type(8)));
typedef float  f32x4  __attribute__((ext_vector_type(4)));
typedef unsigned short u16x4 __attribute__((ext_vector_type(4)));

__device__ __forceinline__ unsigned short f2bf(float f) {
  unsigned u = __builtin_bit_cast(unsigned, f);
  u += 0x7FFFu + ((u >> 16) & 1u);          // round-to-nearest-even
  return (unsigned short)(u >> 16);
}

__device__ __forceinline__ int bucket_of(int v) {
  return (v < 0) ? -1 : (v >= 200000) ? 3 : (v >= 40000) ? 2 : (v >= 20000) ? 1 : 0;
}

// ---------------------------------------------------------------------------
// SORTED COMPACTION (3 tiny kernels, zero atomics, fully deterministic).
// Lists are token-ASCENDING within each bucket -> the GEMM writes ascending
// output rows (DRAM row-buffer friendly) instead of random rows.
// NOTE (r11 bug): lists are 4 SEPARATE n-sized segments, so per-bucket
// offsets start at 0 -- no cross-bucket base!
// ---------------------------------------------------------------------------
// 1a: per-block per-bucket counts. NB = ceil(n/256) blocks (64 for n=16384).
__global__ __launch_bounds__(256) void count_kernel(const int* __restrict__ inp, int n,
                                                    int* __restrict__ blkcnt) {
  int t = blockIdx.x * 256 + threadIdx.x;
  int lane = threadIdx.x & 63, w = threadIdx.x >> 6;
  int v = (t < n) ? inp[t] : -1;
  int b = bucket_of(v);
  __shared__ int cnt[4][4];                 // [wave][bucket]
#pragma unroll
  for (int i = 0; i < 4; ++i) {
    unsigned long long m = __ballot(b == i);
    if (lane == 0) cnt[w][i] = __popcll(m);
  }
  __syncthreads();
  if (threadIdx.x < 4) {
    int s = cnt[0][threadIdx.x] + cnt[1][threadIdx.x] +
            cnt[2][threadIdx.x] + cnt[3][threadIdx.x];
    blkcnt[blockIdx.x * 4 + threadIdx.x] = s;
  }
}

// 1b: scan. 1 block, 4 waves; wave b scans bucket b across NB (<=64) blocks.
// off[blk][b] = exclusive prefix WITHIN bucket b; counts[b] = totals.
__global__ __launch_bounds__(256) void scan_kernel(const int* __restrict__ blkcnt, int nb,
                                                   int* __restrict__ off,
                                                   int* __restrict__ counts) {
  int lane = threadIdx.x & 63, b = threadIdx.x >> 6;
  int v = (lane < nb) ? blkcnt[lane * 4 + b] : 0;
  int x = v;
#pragma unroll
  for (int d = 1; d < 64; d <<= 1) {        // inclusive scan over 64 lanes
    int y = __shfl_up(x, d);
    if (lane >= d) x += y;
  }
  if (lane < nb) off[lane * 4 + b] = x - v; // exclusive, per-bucket (base 0)
  if (lane == 63) counts[b] = x;            // bucket total
}

// 1c: scatter. Stable by construction (block-prefix + wave-prefix + lane-rank
// all ordered by tid) -> token-ascending within each bucket.
// Entry packs (in-bucket row << 14) | token_id  (n = 16384 = 2^14).
__global__ __launch_bounds__(256) void scatter_kernel(const int* __restrict__ inp, int n,
                                                      const int* __restrict__ off,
                                                      unsigned* __restrict__ lists) {
  int t = blockIdx.x * 256 + threadIdx.x;
  int lane = threadIdx.x & 63, w = threadIdx.x >> 6;
  int v = (t < n) ? inp[t] : -1;
  int b = bucket_of(v);
  int lo = (b == 3) ? 200000 : (b == 2) ? 40000 : (b == 1) ? 20000 : 0;
  __shared__ int cnt[4][4];
  int myrank = 0;
#pragma unroll
  for (int i = 0; i < 4; ++i) {
    unsigned long long m = __ballot(b == i);
    if (lane == 0) cnt[w][i] = __popcll(m);
    if (b == i) myrank = __popcll(m & ((1ull << lane) - 1ull));
  }
  __syncthreads();
  if (b >= 0) {
    int prefix = 0;
    for (int w2 = 0; w2 < w; ++w2) prefix += cnt[w2][b];
    int pos = off[blockIdx.x * 4 + b] + prefix + myrank;
    lists[(size_t)b * n + pos] = ((unsigned)(v - lo) << 14) | (unsigned)t;
  }
}

// ---------------------------------------------------------------------------
// Heavy path (D % 64 == 0): full-K, single LDS buffer, pipelined staging
// (next chunk's 12 float4 loads issued right after the barrier, in flight
// across ds_read+MFMA). LDS bf16 tiles XOR-swizzled byte ^= (row&7)<<4
// (G4: 128B rows else 16-way conflict on ds_read_b128). [verbatim r9]
// ---------------------------------------------------------------------------
template <int D>
__device__ __forceinline__ void gemm_heavy(const float* __restrict__ emb,
                                           const float* __restrict__ proj,
                                           const unsigned* __restrict__ list,
                                           int cnt, int r0, int c0,
                                           float* __restrict__ out, char* smem) {
  constexpr int NCH = D / 64;
  const int tid  = threadIdx.x;
  const int lane = tid & 63;
  const int w    = tid >> 6;
  const int wr   = w >> 1, wc = w & 1;     // 2x2 wave grid: 32 rows x 64 cols
  const int lr   = lane & 15, t16 = lane >> 4;

  char* Ab = smem;                          // A: 64 x 128 B  =  8 KB
  char* Bb = smem + 8192;                   // B: 128 x 128 B = 16 KB
  unsigned* toks = (unsigned*)(smem + 24576);

  if (tid < 64) {
    int p = r0 + tid;
    toks[tid] = (p < cnt) ? list[p] : 0u;   // pads -> row 0 (stores suppressed)
  }
  __syncthreads();

  int ra[4], ca[4], cb[8], c4b[8];
#pragma unroll
  for (int i = 0; i < 4; ++i) {
    int q = tid + i * 256;
    ra[i] = q >> 4; ca[i] = (q & 15) * 4;
  }
#pragma unroll
  for (int i = 0; i < 8; ++i) {
    int q = tid + i * 256;
    cb[i] = q >> 4; c4b[i] = (q & 15) * 4;
  }
  const float* abase[4];
#pragma unroll
  for (int i = 0; i < 4; ++i)
    abase[i] = emb + (size_t)(toks[ra[i]] >> 14) * D + ca[i];
  const float* bbase[8];
#pragma unroll
  for (int i = 0; i < 8; ++i)
    bbase[i] = proj + (size_t)(c0 + cb[i]) * D + c4b[i];

  float4 arg[4], brg[8];
#pragma unroll
  for (int i = 0; i < 4; ++i) arg[i] = *reinterpret_cast<const float4*>(abase[i]);
#pragma unroll
  for (int i = 0; i < 8; ++i) brg[i] = *reinterpret_cast<const float4*>(bbase[i]);

  f32x4 acc[2][4];
#pragma unroll
  for (int fi = 0; fi < 2; ++fi)
#pragma unroll
    for (int fj = 0; fj < 4; ++fj) acc[fi][fj] = (f32x4){0.f, 0.f, 0.f, 0.f};

  for (int ch = 0; ch < NCH; ++ch) {
#pragma unroll
    for (int i = 0; i < 4; ++i) {
      u16x4 o = {f2bf(arg[i].x), f2bf(arg[i].y), f2bf(arg[i].z), f2bf(arg[i].w)};
      *reinterpret_cast<u16x4*>(Ab + ra[i] * 128 + ((ca[i] * 2) ^ ((ra[i] & 7) << 4))) = o;
    }
#pragma unroll
    for (int i = 0; i < 8; ++i) {
      u16x4 o = {f2bf(brg[i].x), f2bf(brg[i].y), f2bf(brg[i].z), f2bf(brg[i].w)};
      *reinterpret_cast<u16x4*>(Bb + cb[i] * 128 + ((c4b[i] * 2) ^ ((cb[i] & 7) << 4))) = o;
    }
    __syncthreads();

    if (ch + 1 < NCH) {
      const int k1 = (ch + 1) * 64;
#pragma unroll
      for (int i = 0; i < 4; ++i) arg[i] = *reinterpret_cast<const float4*>(abase[i] + k1);
#pragma unroll
      for (int i = 0; i < 8; ++i) brg[i] = *reinterpret_cast<const float4*>(bbase[i] + k1);
    }

#pragma unroll
    for (int s = 0; s < 2; ++s) {
      bf16x8 a[2], b[4];
#pragma unroll
      for (int fi = 0; fi < 2; ++fi) {
        int row = wr * 32 + fi * 16 + lr;
        a[fi] = *reinterpret_cast<const bf16x8*>(
            Ab + row * 128 + ((s * 64 + t16 * 16) ^ ((row & 7) << 4)));
      }
#pragma unroll
      for (int fj = 0; fj < 4; ++fj) {
        int col = wc * 64 + fj * 16 + lr;
        b[fj] = *reinterpret_cast<const bf16x8*>(
            Bb + col * 128 + ((s * 64 + t16 * 16) ^ ((col & 7) << 4)));
      }
#pragma unroll
      for (int fi = 0; fi < 2; ++fi)
#pragma unroll
        for (int fj = 0; fj < 4; ++fj)
          acc[fi][fj] = __builtin_amdgcn_mfma_f32_16x16x32_bf16(a[fi], b[fj], acc[fi][fj], 0, 0, 0);
    }
    __syncthreads();
  }

  float* T = reinterpret_cast<float*>(smem + w * 4352);  // 16 x stride 68
#pragma unroll
  for (int fi = 0; fi < 2; ++fi) {
#pragma unroll
    for (int fj = 0; fj < 4; ++fj)
#pragma unroll
      for (int reg = 0; reg < 4; ++reg)
        T[(t16 * 4 + reg) * 68 + fj * 16 + lr] = acc[fi][fj][reg];
#pragma unroll
    for (int rr = 0; rr < 4; ++rr) {
      int p = wr * 32 + fi * 16 + rr * 4 + t16;
      if (r0 + p < cnt) {
        float4 v = *reinterpret_cast<const float4*>(&T[(rr * 4 + t16) * 68 + lr * 4]);
        *reinterpret_cast<float4*>(out + (size_t)(toks[p] & 16383u) * DPROJ +
                                   c0 + wc * 64 + lr * 4) = v;
      }
    }
  }
}

// ---------------------------------------------------------------------------
// Light path (D = 64 or 16): register-direct fragments, one barrier. [r9]
// ---------------------------------------------------------------------------
template <int D>
__device__ __forceinline__ void gemm_light(const float* __restrict__ emb,
                                           const float* __restrict__ proj,
                                           const unsigned* __restrict__ list,
                                           int cnt, int r0, int c0,
                                           float* __restrict__ out, char* smem) {
  constexpr int S = (D == 64) ? 2 : 1;
  const int tid  = threadIdx.x;
  const int lane = tid & 63;
  const int w    = tid >> 6;
  const int wr   = w >> 1, wc = w & 1;
  const int lr   = lane & 15, t16 = lane >> 4;

  unsigned* toks = (unsigned*)smem;
  if (tid < 64) {
    int p = r0 + tid;
    toks[tid] = (p < cnt) ? list[p] : 0u;
  }
  __syncthreads();

  bf16x8 a[2][S], b[4][S];
#pragma unroll
  for (int fi = 0; fi < 2; ++fi) {
    const float* eb = emb + (size_t)(toks[wr * 32 + fi * 16 + lr] >> 14) * D;
#pragma unroll
    for (int s = 0; s < S; ++s) {
      float4 lo = make_float4(0.f, 0.f, 0.f, 0.f), hi = lo;
      if (D == 64 || t16 < 2) {
        lo = *reinterpret_cast<const float4*>(eb + s * 32 + t16 * 8);
        hi = *reinterpret_cast<const float4*>(eb + s * 32 + t16 * 8 + 4);
      }
      bf16x8 r;
      r[0] = (short)f2bf(lo.x); r[1] = (short)f2bf(lo.y);
      r[2] = (short)f2bf(lo.z); r[3] = (short)f2bf(lo.w);
      r[4] = (short)f2bf(hi.x); r[5] = (short)f2bf(hi.y);
      r[6] = (short)f2bf(hi.z); r[7] = (short)f2bf(hi.w);
      a[fi][s] = r;
    }
  }
#pragma unroll
  for (int fj = 0; fj < 4; ++fj) {
    const float* pb = proj + (size_t)(c0 + wc * 64 + fj * 16 + lr) * D;
#pragma unroll
    for (int s = 0; s < S; ++s) {
      float4 lo = make_float4(0.f, 0.f, 0.f, 0.f), hi = lo;
      if (D == 64 || t16 < 2) {
        lo = *reinterpret_cast<const float4*>(pb + s * 32 + t16 * 8);
        hi = *reinterpret_cast<const float4*>(pb + s * 32 + t16 * 8 + 4);
      }
      bf16x8 r;
      r[0] = (short)f2bf(lo.x); r[1] = (short)f2bf(lo.y);
      r[2] = (short)f2bf(lo.z); r[3] = (short)f2bf(lo.w);
      r[4] = (short)f2bf(hi.x); r[5] = (short)f2bf(hi.y);
      r[6] = (short)f2bf(hi.z); r[7] = (short)f2bf(hi.w);
      b[fj][s] = r;
    }
  }

  f32x4 acc[2][4];
#pragma unroll
  for (int fi = 0; fi < 2; ++fi)
#pragma unroll
    for (int fj = 0; fj < 4; ++fj) acc[fi][fj] = (f32x4){0.f, 0.f, 0.f, 0.f};
#pragma unroll
  for (int s = 0; s < S; ++s)
#pragma unroll
    for (int fi = 0; fi < 2; ++fi)
#pragma unroll
      for (int fj = 0; fj < 4; ++fj)
        acc[fi][fj] = __builtin_amdgcn_mfma_f32_16x16x32_bf16(a[fi][s], b[fj][s], acc[fi][fj], 0, 0, 0);

  float* T = reinterpret_cast<float*>(smem + 256) + w * 1088;
#pragma unroll
  for (int fi = 0; fi < 2; ++fi) {
#pragma unroll
    for (int fj = 0; fj < 4; ++fj)
#pragma unroll
      for (int reg = 0; reg < 4; ++reg)
        T[(t16 * 4 + reg) * 68 + fj * 16 + lr] = acc[fi][fj][reg];
#pragma unroll
    for (int rr = 0; rr < 4; ++rr) {
      int p = wr * 32 + fi * 16 + rr * 4 + t16;
      if (r0 + p < cnt) {
        float4 v = *reinterpret_cast<const float4*>(&T[(rr * 4 + t16) * 68 + lr * 4]);
        *reinterpret_cast<float4*>(out + (size_t)(toks[p] & 16383u) * DPROJ +
                                   c0 + wc * 64 + lr * 4) = v;
      }
    }
  }
}

// ---------------------------------------------------------------------------
// Dispatcher: 1-D grid, XCD-grouping decode (r9): the 8 col-slices of a
// row-tile share an XCD and are co-resident -> L2 assembles full 4 KB rows.
// tile = (bx>>6)*8 + (bx&7); cslice = (bx>>3)&7. Heavy tiles first.
// ---------------------------------------------------------------------------
__global__ __launch_bounds__(256) void gemm_all(
    const float* __restrict__ e0, const float* __restrict__ p0,
    const float* __restrict__ e1, const float* __restrict__ p1,
    const float* __restrict__ e2, const float* __restrict__ p2,
    const float* __restrict__ e3, const float* __restrict__ p3,
    const int* __restrict__ counts, const unsigned* __restrict__ lists,
    float* __restrict__ out, int n) {
  extern __shared__ char smem[];
  int bx = blockIdx.x;
  int t  = ((bx >> 6) << 3) + (bx & 7);
  int c0 = ((bx >> 3) & 7) * 128;
  int4 c = *reinterpret_cast<const int4*>(counts);
  int t0 = (c.x + 63) >> 6, t1 = (c.y + 63) >> 6,
      t2 = (c.z + 63) >> 6, t3 = (c.w + 63) >> 6;
  if (t < t0) { gemm_heavy<1024>(e0, p0, lists,               c.x, t * 64, c0, out, smem); return; }
  t -= t0;
  if (t < t1) { gemm_heavy< 256>(e1, p1, lists + (size_t)n,   c.y, t * 64, c0, out, smem); return; }
  t -= t1;
  if (t < t2) { gemm_light<64>(e2, p2, lists + (size_t)2 * n, c.z, t * 64, c0, out, smem); return; }
  t -= t2;
  if (t < t3) { gemm_light<16>(e3, p3, lists + (size_t)3 * n, c.w, t * 64, c0, out, smem); return; }
}

// ---------------------------------------------------------------------------
// Input order (setup_inputs dict order, verified rounds 1-11):
// inp, emb0, proj0, emb1, proj1, emb2, proj2, emb3, proj3.
// ws layout (ints): [0..3] counts, [4..259] blkcnt, [260..515] off,
// [516..] lists (4n).
// ---------------------------------------------------------------------------
extern "C" void kernel_launch(void* const* d_in, const int* in_sizes, int n_in,
                              void* d_out, int out_size, void* d_ws, size_t ws_size,
                              hipStream_t stream) {
  const int*   inp   = (const int*)d_in[0];
  const float* emb0  = (const float*)d_in[1];
  const float* proj0 = (const float*)d_in[2];
  const float* emb1  = (const float*)d_in[3];
  const float* proj1 = (const float*)d_in[4];
  const float* emb2  = (const float*)d_in[5];
  const float* proj2 = (const float*)d_in[6];
  const float* emb3  = (const float*)d_in[7];
  const float* proj3 = (const float*)d_in[8];
  float* out = (float*)d_out;
  const int n = in_sizes[0];  // 16384 tokens

  int*      counts = (int*)d_ws;
  int*      blkcnt = (int*)d_ws + 4;
  int*      off    = (int*)d_ws + 260;
  unsigned* lists  = (unsigned*)d_ws + 516;

  const int nb = (n + 255) / 256;           // 64 (scan supports <= 64)
  count_kernel<<<dim3(nb), dim3(256), 0, stream>>>(inp, n, blkcnt);
  scan_kernel<<<dim3(1), dim3(256), 0, stream>>>(blkcnt, nb, off, counts);
  scatter_kernel<<<dim3(nb), dim3(256), 0, stream>>>(inp, n, off, lists);

  // tiles: sum_i ceil(cnt_i/64) <= n/64 + 3 = 259; pad to 264 (multiple of 8).
  dim3 grid(264 * 8, 1, 1);
  size_t smem_bytes = 24576 + 64 * sizeof(unsigned);  // 24832 B
  gemm_all<<<grid, dim3(256), smem_bytes, stream>>>(emb0, proj0, emb1, proj1,
                                                    emb2, proj2, emb3, proj3,
                                                    counts, lists, out, n);
}